// Round 10
// baseline (227.106 us; speedup 1.0000x reference)
//
#include <hip/hip_runtime.h>

#define N_FEATS 128
#define HIDDEN 512
#define NPAD 50176       // N rounded to multiple of 256
#define NBKT 196         // dst buckets of 256 nodes
#define SLAB 4608        // staging/csr slots per bucket (4096 avg + 8 sigma)
#define PA_EPB 4096      // bucketA edges per block
#define PA_BLOCKS 196    // ceil(800000/4096)
#define XH_BLOCKS 6250   // N*32 float4 units / 256

typedef __attribute__((ext_vector_type(4))) float floatx4;
typedef __attribute__((ext_vector_type(8))) short shortx8;
typedef __attribute__((ext_vector_type(8))) unsigned short ushortx8;

__device__ __forceinline__ unsigned short f2bf(float f) {
    union { float f; unsigned u; } a; a.f = f;
    unsigned r = a.u + 0x7fff + ((a.u >> 16) & 1);   // RNE
    return (unsigned short)(r >> 16);
}
#define BF(x) ({ union { unsigned u; float f; } _c; _c.u = (unsigned)(x) << 16; _c.f; })

// ---------------- K1: bucketA partition + W1 transpose + Xh convert ----------------
__global__ __launch_bounds__(256) void k_initA(const float* __restrict__ W1,
        unsigned short* __restrict__ w1t, const float* __restrict__ X,
        unsigned short* __restrict__ Xh, const int* __restrict__ src,
        const int* __restrict__ dst, int* __restrict__ bcur,
        unsigned* __restrict__ staging, int E, int N) {
    int b = blockIdx.x, tid = threadIdx.x;
    if (b < PA_BLOCKS) {
        __shared__ int hist[NBKT];
        __shared__ int base[NBKT];
        for (int i = tid; i < NBKT; i += 256) hist[i] = 0;
        __syncthreads();
        #pragma unroll
        for (int i = 0; i < 4; ++i) {
            int e = b * PA_EPB + (i * 256 + tid) * 4;
            if (e + 3 < E) {
                int4 d4 = *reinterpret_cast<const int4*>(dst + e);
                atomicAdd(&hist[d4.x >> 8], 1);
                atomicAdd(&hist[d4.y >> 8], 1);
                atomicAdd(&hist[d4.z >> 8], 1);
                atomicAdd(&hist[d4.w >> 8], 1);
            } else {
                for (int k = 0; k < 4; ++k)
                    if (e + k < E) atomicAdd(&hist[dst[e + k] >> 8], 1);
            }
        }
        __syncthreads();
        for (int i = tid; i < NBKT; i += 256) {
            int c = hist[i];
            base[i] = c ? atomicAdd(&bcur[i], c) : 0;
            hist[i] = 0;
        }
        __syncthreads();
        #pragma unroll
        for (int i = 0; i < 4; ++i) {
            int e = b * PA_EPB + (i * 256 + tid) * 4;
            if (e + 3 < E) {
                int4 d4 = *reinterpret_cast<const int4*>(dst + e);
                int4 s4 = *reinterpret_cast<const int4*>(src + e);
                #define PUT(dd, ss) { int bk = (dd) >> 8; int r = atomicAdd(&hist[bk], 1); \
                    int pos = base[bk] + r; if (pos < SLAB) \
                    staging[(size_t)bk * SLAB + pos] = ((unsigned)(ss) << 8) | (unsigned)((dd) & 255); }
                PUT(d4.x, s4.x) PUT(d4.y, s4.y) PUT(d4.z, s4.z) PUT(d4.w, s4.w)
            } else {
                for (int k = 0; k < 4; ++k)
                    if (e + k < E) { int dd = dst[e + k], ss = src[e + k]; PUT(dd, ss) }
                #undef PUT
            }
        }
    } else if (b < PA_BLOCKS + 16) {
        __shared__ unsigned short t[64][65];
        int bb = b - PA_BLOCKS;
        int ki = bb >> 3, ni = bb & 7;
        #pragma unroll
        for (int i = 0; i < 16; ++i) {
            int idx = tid + i * 256;
            int r = idx >> 6, c = idx & 63;
            t[r][c] = f2bf(W1[(ki * 64 + r) * 512 + ni * 64 + c]);
        }
        __syncthreads();
        #pragma unroll
        for (int i = 0; i < 16; ++i) {
            int idx = tid + i * 256;
            int rn = idx >> 6, ck = idx & 63;
            w1t[(ni * 64 + rn) * 128 + ki * 64 + ck] = t[ck][rn];
        }
    } else {
        int idx = (b - PA_BLOCKS - 16) * 256 + tid;
        if (idx < N * 32) {
            float4 v = reinterpret_cast<const float4*>(X)[idx];
            ushort4 o;
            o.x = f2bf(v.x); o.y = f2bf(v.y); o.z = f2bf(v.z); o.w = f2bf(v.w);
            reinterpret_cast<ushort4*>(Xh)[idx] = o;
        }
    }
}

// ---------------- K2: per-bucket compact-CSR build; emit offs_g/cursor/dinvs ----------------
__global__ __launch_bounds__(256) void k_bucketB(const int* __restrict__ bcur,
        const unsigned* __restrict__ staging, int* __restrict__ csr_g,
        int* __restrict__ offs_g, int* __restrict__ cursor, float* __restrict__ dinvs) {
    __shared__ int hist[256];
    __shared__ int offs_l[256];
    __shared__ int sc[256];
    int b = blockIdx.x, tid = threadIdx.x;
    hist[tid] = 0;
    __syncthreads();
    int cnt = bcur[b];
    if (cnt > SLAB) cnt = SLAB;
    const unsigned* st = staging + (size_t)b * SLAB;
    for (int j = tid; j < cnt; j += 256) atomicAdd(&hist[st[j] & 255u], 1);
    __syncthreads();
    int c = hist[tid];
    sc[tid] = c;
    __syncthreads();
    #pragma unroll
    for (int off = 1; off < 256; off <<= 1) {
        int t = (tid >= off) ? sc[tid - off] : 0;
        __syncthreads();
        sc[tid] += t;
        __syncthreads();
    }
    int excl = sc[tid] - c;
    offs_l[tid] = excl;
    int node = (b << 8) + tid;
    cursor[node] = c;
    dinvs[node] = rsqrtf((float)c + 1.0f);
    offs_g[node] = b * SLAB + excl;
    hist[tid] = 0;
    __syncthreads();
    for (int j = tid; j < cnt; j += 256) {
        unsigned v = st[j];
        int dl = (int)(v & 255u);
        int s = (int)(v >> 8);
        int p = atomicAdd(&hist[dl], 1);
        csr_g[b * SLAB + offs_l[dl] + p] = s;
    }
}

// ---------------- K3: fused gather + MFMA GEMM -> lps ----------------
// 392 blocks x 512 threads; 128 nodes/block. LDS = As only (+b1/W2): 40 KB -> 3 blocks/CU.
// B fragments read directly from w1t (L1/L2-hot, reused by all blocks).
__global__ __launch_bounds__(512, 6) void k_gather_gemm(
        const int* __restrict__ cursor, const float* __restrict__ dinvs,
        const int* __restrict__ offs_g, const int* __restrict__ csr_g,
        const unsigned short* __restrict__ Xh, const unsigned short* __restrict__ w1t,
        const float* __restrict__ b1, const float* __restrict__ W2,
        float2* __restrict__ lps, int N) {
    __shared__ unsigned short As[128][136];   // 34.8 KB
    __shared__ float b1s[HIDDEN];             // 2 KB
    __shared__ float W2s[HIDDEN * 2];         // 4 KB

    const int tid = threadIdx.x;
    const int m0 = blockIdx.x * 128;
    for (int i = tid; i < HIDDEN; i += 512) b1s[i] = b1[i];
    for (int i = tid; i < HIDDEN * 2; i += 512) W2s[i] = W2[i];

    union U8 { ushortx8 v; unsigned short s[8]; };

    // ---- gather phase: 4 passes x (32 nodes x 16 lanes); 1 b128/lane covers a 256B row ----
    const int lane16 = tid & 15;
    const int nsub = tid >> 4;                 // 0..31
    const ushortx8* Xv = reinterpret_cast<const ushortx8*>(Xh);
    #pragma unroll
    for (int h = 0; h < 4; ++h) {
        int r = h * 32 + nsub;
        int gm = m0 + r;
        if (gm < N) {
            float dv = dinvs[gm];
            int beg = offs_g[gm];
            int cnt = cursor[gm];
            U8 sv; sv.v = Xv[((size_t)gm << 4) + lane16];
            float a[8];
            #pragma unroll
            for (int k = 0; k < 8; ++k) a[k] = dv * BF(sv.s[k]);
            const int* cp = csr_g + beg;
            int j = 0;
            int4 nxt;
            if (cnt >= 4) nxt = *reinterpret_cast<const int4*>(cp);
            for (; j + 4 <= cnt; j += 4) {
                int4 s4 = nxt;
                if (j + 8 <= cnt) nxt = *reinterpret_cast<const int4*>(cp + j + 4);
                float w0 = dinvs[s4.x], w1 = dinvs[s4.y], w2 = dinvs[s4.z], w3 = dinvs[s4.w];
                U8 u0, u1, u2, u3;
                u0.v = Xv[((size_t)s4.x << 4) + lane16];
                u1.v = Xv[((size_t)s4.y << 4) + lane16];
                u2.v = Xv[((size_t)s4.z << 4) + lane16];
                u3.v = Xv[((size_t)s4.w << 4) + lane16];
                #pragma unroll
                for (int k = 0; k < 8; ++k)
                    a[k] += w0 * BF(u0.s[k]) + w1 * BF(u1.s[k]) + w2 * BF(u2.s[k]) + w3 * BF(u3.s[k]);
            }
            for (; j < cnt; ++j) {
                int s = cp[j];
                float w = dinvs[s];
                U8 u; u.v = Xv[((size_t)s << 4) + lane16];
                #pragma unroll
                for (int k = 0; k < 8; ++k) a[k] += w * BF(u.s[k]);
            }
            union { shortx8 v; unsigned short s[8]; } o;
            #pragma unroll
            for (int k = 0; k < 8; ++k) o.s[k] = f2bf(a[k] * dv);
            *reinterpret_cast<shortx8*>(&As[r][lane16 * 8]) = o.v;
        } else {
            shortx8 z = {0, 0, 0, 0, 0, 0, 0, 0};
            *reinterpret_cast<shortx8*>(&As[r][lane16 * 8]) = z;
        }
    }
    __syncthreads();

    // ---- GEMM phase: 8 waves x 16-row strips; B from global (no Bs, no more barriers) ----
    const int wave = tid >> 6;
    const int lane64 = tid & 63;
    const int quad = lane64 >> 4;
    const int l16 = lane64 & 15;
    const unsigned short* wb = w1t + (size_t)l16 * 128 + quad * 8;

    float accL0[4] = {0.f, 0.f, 0.f, 0.f};
    float accL1[4] = {0.f, 0.f, 0.f, 0.f};

    #pragma unroll
    for (int n0 = 0; n0 < HIDDEN; n0 += 128) {
        floatx4 acc[8];
        #pragma unroll
        for (int nt = 0; nt < 8; ++nt) acc[nt] = (floatx4){0.f, 0.f, 0.f, 0.f};

        #pragma unroll
        for (int ks = 0; ks < 4; ++ks) {
            shortx8 af = *reinterpret_cast<const shortx8*>(&As[wave * 16 + l16][ks * 32 + quad * 8]);
            #pragma unroll
            for (int nt = 0; nt < 8; ++nt) {
                shortx8 bf = *reinterpret_cast<const shortx8*>(wb + (size_t)(n0 + nt * 16) * 128 + ks * 32);
                acc[nt] = __builtin_amdgcn_mfma_f32_16x16x32_bf16(af, bf, acc[nt], 0, 0, 0);
            }
        }

        #pragma unroll
        for (int nt = 0; nt < 8; ++nt) {
            int col = n0 + nt * 16 + l16;
            float bb = b1s[col];
            float w20 = W2s[col * 2 + 0];
            float w21 = W2s[col * 2 + 1];
            #pragma unroll
            for (int r = 0; r < 4; ++r) {
                float hh = acc[nt][r] + bb;
                hh = hh > 0.f ? hh : 0.f;
                accL0[r] += hh * w20;
                accL1[r] += hh * w21;
            }
        }
    }

    #pragma unroll
    for (int off = 1; off < 16; off <<= 1) {
        #pragma unroll
        for (int r = 0; r < 4; ++r) {
            accL0[r] += __shfl_xor(accL0[r], off);
            accL1[r] += __shfl_xor(accL1[r], off);
        }
    }
    if (l16 == 0) {
        #pragma unroll
        for (int r = 0; r < 4; ++r) {
            int gm = m0 + wave * 16 + quad * 4 + r;
            if (gm < N) {
                float dv = dinvs[gm];
                lps[gm] = make_float2(dv * accL0[r], dv * accL1[r]);
            }
        }
    }
}

// ---------------- K4: layer-2 CSR gather + self-loop + bias + softmax ----------------
__global__ __launch_bounds__(256) void k_final(const int* __restrict__ cursor,
        const float* __restrict__ dinvs, const int* __restrict__ offs_g,
        const int* __restrict__ csr_g, const float2* __restrict__ lps,
        const float* __restrict__ b2, float* __restrict__ out, int N) {
    int t = blockIdx.x * 256 + threadIdx.x;
    int node = t >> 3;
    int lane = t & 7;
    if (node >= N) return;
    int cnt = cursor[node];
    int beg = offs_g[node];
    float a0 = 0.f, a1 = 0.f;
    for (int j = lane; j < cnt; j += 8) {
        float2 v = lps[csr_g[beg + j]];
        a0 += v.x;
        a1 += v.y;
    }
    #pragma unroll
    for (int off = 1; off < 8; off <<= 1) {
        a0 += __shfl_xor(a0, off);
        a1 += __shfl_xor(a1, off);
    }
    if (lane == 0) {
        float dv = dinvs[node];
        float2 self = lps[node];
        float l0 = dv * (a0 + self.x) + b2[0];
        float l1 = dv * (a1 + self.y) + b2[1];
        float m = fmaxf(l0, l1);
        float e0 = __expf(l0 - m), e1 = __expf(l1 - m);
        float inv = 1.0f / (e0 + e1);
        out[(size_t)node * 2 + 0] = e0 * inv;
        out[(size_t)node * 2 + 1] = e1 * inv;
    }
}

extern "C" void kernel_launch(void* const* d_in, const int* in_sizes, int n_in,
                              void* d_out, int out_size, void* d_ws, size_t ws_size,
                              hipStream_t stream) {
    const float* X  = (const float*)d_in[0];
    const int* ei   = (const int*)d_in[1];
    const float* W1 = (const float*)d_in[2];
    const float* b1 = (const float*)d_in[3];
    const float* W2 = (const float*)d_in[4];
    const float* b2 = (const float*)d_in[5];
    float* out = (float*)d_out;

    const int N = in_sizes[0] / N_FEATS;   // 50000
    const int E = in_sizes[1] / 2;         // 800000
    const int* src = ei;
    const int* dst = ei + E;

    // workspace layout (16B-aligned segments), ~22 MB
    int* cursor  = (int*)d_ws;                                   // NPAD
    int* bcur    = cursor + NPAD;                                // 256
    int* offs_g  = bcur + 256;                                   // NPAD
    float* dinvs = (float*)(offs_g + NPAD);                      // NPAD
    float2* lps  = (float2*)(dinvs + NPAD);                      // NPAD float2
    unsigned short* w1t = (unsigned short*)(lps + NPAD);         // 512*128
    unsigned short* Xh  = w1t + 512 * 128;                       // NPAD*128
    unsigned* staging = (unsigned*)(Xh + (size_t)NPAD * 128);    // NBKT*SLAB
    int* csr_g   = (int*)(staging + (size_t)NBKT * SLAB);        // NBKT*SLAB

    hipMemsetAsync(bcur, 0, 256 * sizeof(int), stream);
    k_initA      <<<PA_BLOCKS + 16 + XH_BLOCKS, 256, 0, stream>>>(
                     W1, w1t, X, Xh, src, dst, bcur, staging, E, N);
    k_bucketB    <<<NBKT, 256, 0, stream>>>(bcur, staging, csr_g, offs_g, cursor, dinvs);
    k_gather_gemm<<<NPAD / 128, 512, 0, stream>>>(cursor, dinvs, offs_g, csr_g,
                     Xh, w1t, b1, W2, lps, N);
    k_final      <<<((size_t)N * 8 + 255) / 256, 256, 0, stream>>>(
                     cursor, dinvs, offs_g, csr_g, lps, b2, out, N);
}

// Round 11
// 210.824 us; speedup vs baseline: 1.0772x; 1.0772x over previous
//
#include <hip/hip_runtime.h>

#define N_FEATS 128
#define HIDDEN 512
#define NPAD 50176       // N rounded to multiple of 256
#define NBKT 196         // dst buckets of 256 nodes
#define SLAB 4608        // staging/csr slots per bucket (4096 avg + 8 sigma)
#define PA_EPB 4096      // bucketA edges per block
#define PA_BLOCKS 196    // ceil(800000/4096)
#define XH_BLOCKS 6250   // N*32 float4 units / 256

typedef __attribute__((ext_vector_type(4))) float floatx4;
typedef __attribute__((ext_vector_type(8))) short shortx8;
typedef __attribute__((ext_vector_type(8))) unsigned short ushortx8;

__device__ __forceinline__ unsigned short f2bf(float f) {
    union { float f; unsigned u; } a; a.f = f;
    unsigned r = a.u + 0x7fff + ((a.u >> 16) & 1);   // RNE
    return (unsigned short)(r >> 16);
}
#define BF(x) ({ union { unsigned u; float f; } _c; _c.u = (unsigned)(x) << 16; _c.f; })

// ---------------- K1: bucketA partition + W1 transpose + Xh convert ----------------
__global__ __launch_bounds__(256) void k_initA(const float* __restrict__ W1,
        unsigned short* __restrict__ w1t, const float* __restrict__ X,
        unsigned short* __restrict__ Xh, const int* __restrict__ src,
        const int* __restrict__ dst, int* __restrict__ bcur,
        unsigned* __restrict__ staging, int E, int N) {
    int b = blockIdx.x, tid = threadIdx.x;
    if (b < PA_BLOCKS) {
        __shared__ int hist[NBKT];
        __shared__ int base[NBKT];
        for (int i = tid; i < NBKT; i += 256) hist[i] = 0;
        __syncthreads();
        #pragma unroll
        for (int i = 0; i < 4; ++i) {
            int e = b * PA_EPB + (i * 256 + tid) * 4;
            if (e + 3 < E) {
                int4 d4 = *reinterpret_cast<const int4*>(dst + e);
                atomicAdd(&hist[d4.x >> 8], 1);
                atomicAdd(&hist[d4.y >> 8], 1);
                atomicAdd(&hist[d4.z >> 8], 1);
                atomicAdd(&hist[d4.w >> 8], 1);
            } else {
                for (int k = 0; k < 4; ++k)
                    if (e + k < E) atomicAdd(&hist[dst[e + k] >> 8], 1);
            }
        }
        __syncthreads();
        for (int i = tid; i < NBKT; i += 256) {
            int c = hist[i];
            base[i] = c ? atomicAdd(&bcur[i], c) : 0;
            hist[i] = 0;
        }
        __syncthreads();
        #pragma unroll
        for (int i = 0; i < 4; ++i) {
            int e = b * PA_EPB + (i * 256 + tid) * 4;
            if (e + 3 < E) {
                int4 d4 = *reinterpret_cast<const int4*>(dst + e);
                int4 s4 = *reinterpret_cast<const int4*>(src + e);
                #define PUT(dd, ss) { int bk = (dd) >> 8; int r = atomicAdd(&hist[bk], 1); \
                    int pos = base[bk] + r; if (pos < SLAB) \
                    staging[(size_t)bk * SLAB + pos] = ((unsigned)(ss) << 8) | (unsigned)((dd) & 255); }
                PUT(d4.x, s4.x) PUT(d4.y, s4.y) PUT(d4.z, s4.z) PUT(d4.w, s4.w)
            } else {
                for (int k = 0; k < 4; ++k)
                    if (e + k < E) { int dd = dst[e + k], ss = src[e + k]; PUT(dd, ss) }
                #undef PUT
            }
        }
    } else if (b < PA_BLOCKS + 16) {
        __shared__ unsigned short t[64][65];
        int bb = b - PA_BLOCKS;
        int ki = bb >> 3, ni = bb & 7;
        #pragma unroll
        for (int i = 0; i < 16; ++i) {
            int idx = tid + i * 256;
            int r = idx >> 6, c = idx & 63;
            t[r][c] = f2bf(W1[(ki * 64 + r) * 512 + ni * 64 + c]);
        }
        __syncthreads();
        #pragma unroll
        for (int i = 0; i < 16; ++i) {
            int idx = tid + i * 256;
            int rn = idx >> 6, ck = idx & 63;
            w1t[(ni * 64 + rn) * 128 + ki * 64 + ck] = t[ck][rn];
        }
    } else {
        int idx = (b - PA_BLOCKS - 16) * 256 + tid;
        if (idx < N * 32) {
            float4 v = reinterpret_cast<const float4*>(X)[idx];
            ushort4 o;
            o.x = f2bf(v.x); o.y = f2bf(v.y); o.z = f2bf(v.z); o.w = f2bf(v.w);
            reinterpret_cast<ushort4*>(Xh)[idx] = o;
        }
    }
}

// ---------------- K2: per-bucket compact-CSR build; emit offs_g/cursor/dinvs ----------------
__global__ __launch_bounds__(256) void k_bucketB(const int* __restrict__ bcur,
        const unsigned* __restrict__ staging, int* __restrict__ csr_g,
        int* __restrict__ offs_g, int* __restrict__ cursor, float* __restrict__ dinvs) {
    __shared__ int hist[256];
    __shared__ int offs_l[256];
    __shared__ int sc[256];
    int b = blockIdx.x, tid = threadIdx.x;
    hist[tid] = 0;
    __syncthreads();
    int cnt = bcur[b];
    if (cnt > SLAB) cnt = SLAB;
    const unsigned* st = staging + (size_t)b * SLAB;
    for (int j = tid; j < cnt; j += 256) atomicAdd(&hist[st[j] & 255u], 1);
    __syncthreads();
    int c = hist[tid];
    sc[tid] = c;
    __syncthreads();
    #pragma unroll
    for (int off = 1; off < 256; off <<= 1) {
        int t = (tid >= off) ? sc[tid - off] : 0;
        __syncthreads();
        sc[tid] += t;
        __syncthreads();
    }
    int excl = sc[tid] - c;
    offs_l[tid] = excl;
    int node = (b << 8) + tid;
    cursor[node] = c;
    dinvs[node] = rsqrtf((float)c + 1.0f);
    offs_g[node] = b * SLAB + excl;
    hist[tid] = 0;
    __syncthreads();
    for (int j = tid; j < cnt; j += 256) {
        unsigned v = st[j];
        int dl = (int)(v & 255u);
        int s = (int)(v >> 8);
        int p = atomicAdd(&hist[dl], 1);
        csr_g[b * SLAB + offs_l[dl] + p] = s;
    }
}

// ---------------- K3: fused gather + MFMA GEMM -> lps ----------------
// 784 blocks x 256 threads; 64 nodes/block. LDS = 23.4 KB -> 6 blocks/CU (LDS-bound).
// B fragments read directly from w1t (L2-resident, reused by all blocks).
__global__ __launch_bounds__(256, 6) void k_gather_gemm(
        const int* __restrict__ cursor, const float* __restrict__ dinvs,
        const int* __restrict__ offs_g, const int* __restrict__ csr_g,
        const unsigned short* __restrict__ Xh, const unsigned short* __restrict__ w1t,
        const float* __restrict__ b1, const float* __restrict__ W2,
        float2* __restrict__ lps, int N) {
    __shared__ unsigned short As[64][136];    // 17.4 KB
    __shared__ float b1s[HIDDEN];             // 2 KB
    __shared__ float W2s[HIDDEN * 2];         // 4 KB

    const int tid = threadIdx.x;
    const int m0 = blockIdx.x * 64;
    for (int i = tid; i < HIDDEN; i += 256) b1s[i] = b1[i];
    for (int i = tid; i < HIDDEN * 2; i += 256) W2s[i] = W2[i];

    union U8 { ushortx8 v; unsigned short s[8]; };

    // ---- gather phase: 4 passes x (16 nodes x 16 lanes); 1 b128/lane covers a 256B row ----
    const int lane16 = tid & 15;
    const int nsub = tid >> 4;                 // 0..15
    const ushortx8* Xv = reinterpret_cast<const ushortx8*>(Xh);
    #pragma unroll
    for (int h = 0; h < 4; ++h) {
        int r = h * 16 + nsub;
        int gm = m0 + r;
        if (gm < N) {
            float dv = dinvs[gm];
            int beg = offs_g[gm];
            int cnt = cursor[gm];
            U8 sv; sv.v = Xv[((size_t)gm << 4) + lane16];
            float a[8];
            #pragma unroll
            for (int k = 0; k < 8; ++k) a[k] = dv * BF(sv.s[k]);
            const int* cp = csr_g + beg;
            int j = 0;
            int4 nxt;
            if (cnt >= 4) nxt = *reinterpret_cast<const int4*>(cp);
            for (; j + 4 <= cnt; j += 4) {
                int4 s4 = nxt;
                if (j + 8 <= cnt) nxt = *reinterpret_cast<const int4*>(cp + j + 4);
                float w0 = dinvs[s4.x], w1 = dinvs[s4.y], w2 = dinvs[s4.z], w3 = dinvs[s4.w];
                U8 u0, u1, u2, u3;
                u0.v = Xv[((size_t)s4.x << 4) + lane16];
                u1.v = Xv[((size_t)s4.y << 4) + lane16];
                u2.v = Xv[((size_t)s4.z << 4) + lane16];
                u3.v = Xv[((size_t)s4.w << 4) + lane16];
                #pragma unroll
                for (int k = 0; k < 8; ++k)
                    a[k] += w0 * BF(u0.s[k]) + w1 * BF(u1.s[k]) + w2 * BF(u2.s[k]) + w3 * BF(u3.s[k]);
            }
            for (; j < cnt; ++j) {
                int s = cp[j];
                float w = dinvs[s];
                U8 u; u.v = Xv[((size_t)s << 4) + lane16];
                #pragma unroll
                for (int k = 0; k < 8; ++k) a[k] += w * BF(u.s[k]);
            }
            union { shortx8 v; unsigned short s[8]; } o;
            #pragma unroll
            for (int k = 0; k < 8; ++k) o.s[k] = f2bf(a[k] * dv);
            *reinterpret_cast<shortx8*>(&As[r][lane16 * 8]) = o.v;
        } else {
            shortx8 z = {0, 0, 0, 0, 0, 0, 0, 0};
            *reinterpret_cast<shortx8*>(&As[r][lane16 * 8]) = z;
        }
    }
    __syncthreads();

    // ---- GEMM phase: 4 waves x 16-row strips; B from global (n0 loop NOT unrolled) ----
    const int wave = tid >> 6;
    const int lane64 = tid & 63;
    const int quad = lane64 >> 4;
    const int l16 = lane64 & 15;
    const unsigned short* wb = w1t + (size_t)l16 * 128 + quad * 8;

    float accL0[4] = {0.f, 0.f, 0.f, 0.f};
    float accL1[4] = {0.f, 0.f, 0.f, 0.f};

    for (int n0 = 0; n0 < HIDDEN; n0 += 128) {
        floatx4 acc[8];
        #pragma unroll
        for (int nt = 0; nt < 8; ++nt) acc[nt] = (floatx4){0.f, 0.f, 0.f, 0.f};

        #pragma unroll
        for (int ks = 0; ks < 4; ++ks) {
            shortx8 af = *reinterpret_cast<const shortx8*>(&As[wave * 16 + l16][ks * 32 + quad * 8]);
            #pragma unroll
            for (int nt = 0; nt < 8; ++nt) {
                shortx8 bf = *reinterpret_cast<const shortx8*>(wb + (size_t)(n0 + nt * 16) * 128 + ks * 32);
                acc[nt] = __builtin_amdgcn_mfma_f32_16x16x32_bf16(af, bf, acc[nt], 0, 0, 0);
            }
        }

        #pragma unroll
        for (int nt = 0; nt < 8; ++nt) {
            int col = n0 + nt * 16 + l16;
            float bb = b1s[col];
            float w20 = W2s[col * 2 + 0];
            float w21 = W2s[col * 2 + 1];
            #pragma unroll
            for (int r = 0; r < 4; ++r) {
                float hh = acc[nt][r] + bb;
                hh = hh > 0.f ? hh : 0.f;
                accL0[r] += hh * w20;
                accL1[r] += hh * w21;
            }
        }
    }

    #pragma unroll
    for (int off = 1; off < 16; off <<= 1) {
        #pragma unroll
        for (int r = 0; r < 4; ++r) {
            accL0[r] += __shfl_xor(accL0[r], off);
            accL1[r] += __shfl_xor(accL1[r], off);
        }
    }
    if (l16 == 0) {
        #pragma unroll
        for (int r = 0; r < 4; ++r) {
            int gm = m0 + wave * 16 + quad * 4 + r;
            if (gm < N) {
                float dv = dinvs[gm];
                lps[gm] = make_float2(dv * accL0[r], dv * accL1[r]);
            }
        }
    }
}

// ---------------- K4: layer-2 CSR gather + self-loop + bias + softmax ----------------
__global__ __launch_bounds__(256) void k_final(const int* __restrict__ cursor,
        const float* __restrict__ dinvs, const int* __restrict__ offs_g,
        const int* __restrict__ csr_g, const float2* __restrict__ lps,
        const float* __restrict__ b2, float* __restrict__ out, int N) {
    int t = blockIdx.x * 256 + threadIdx.x;
    int node = t >> 3;
    int lane = t & 7;
    if (node >= N) return;
    int cnt = cursor[node];
    int beg = offs_g[node];
    float a0 = 0.f, a1 = 0.f;
    for (int j = lane; j < cnt; j += 8) {
        float2 v = lps[csr_g[beg + j]];
        a0 += v.x;
        a1 += v.y;
    }
    #pragma unroll
    for (int off = 1; off < 8; off <<= 1) {
        a0 += __shfl_xor(a0, off);
        a1 += __shfl_xor(a1, off);
    }
    if (lane == 0) {
        float dv = dinvs[node];
        float2 self = lps[node];
        float l0 = dv * (a0 + self.x) + b2[0];
        float l1 = dv * (a1 + self.y) + b2[1];
        float m = fmaxf(l0, l1);
        float e0 = __expf(l0 - m), e1 = __expf(l1 - m);
        float inv = 1.0f / (e0 + e1);
        out[(size_t)node * 2 + 0] = e0 * inv;
        out[(size_t)node * 2 + 1] = e1 * inv;
    }
}

extern "C" void kernel_launch(void* const* d_in, const int* in_sizes, int n_in,
                              void* d_out, int out_size, void* d_ws, size_t ws_size,
                              hipStream_t stream) {
    const float* X  = (const float*)d_in[0];
    const int* ei   = (const int*)d_in[1];
    const float* W1 = (const float*)d_in[2];
    const float* b1 = (const float*)d_in[3];
    const float* W2 = (const float*)d_in[4];
    const float* b2 = (const float*)d_in[5];
    float* out = (float*)d_out;

    const int N = in_sizes[0] / N_FEATS;   // 50000
    const int E = in_sizes[1] / 2;         // 800000
    const int* src = ei;
    const int* dst = ei + E;

    // workspace layout (16B-aligned segments), ~22 MB
    int* cursor  = (int*)d_ws;                                   // NPAD
    int* bcur    = cursor + NPAD;                                // 256
    int* offs_g  = bcur + 256;                                   // NPAD
    float* dinvs = (float*)(offs_g + NPAD);                      // NPAD
    float2* lps  = (float2*)(dinvs + NPAD);                      // NPAD float2
    unsigned short* w1t = (unsigned short*)(lps + NPAD);         // 512*128
    unsigned short* Xh  = w1t + 512 * 128;                       // NPAD*128
    unsigned* staging = (unsigned*)(Xh + (size_t)NPAD * 128);    // NBKT*SLAB
    int* csr_g   = (int*)(staging + (size_t)NBKT * SLAB);        // NBKT*SLAB

    hipMemsetAsync(bcur, 0, 256 * sizeof(int), stream);
    k_initA      <<<PA_BLOCKS + 16 + XH_BLOCKS, 256, 0, stream>>>(
                     W1, w1t, X, Xh, src, dst, bcur, staging, E, N);
    k_bucketB    <<<NBKT, 256, 0, stream>>>(bcur, staging, csr_g, offs_g, cursor, dinvs);
    k_gather_gemm<<<NPAD / 64, 256, 0, stream>>>(cursor, dinvs, offs_g, csr_g,
                     Xh, w1t, b1, W2, lps, N);
    k_final      <<<((size_t)N * 8 + 255) / 256, 256, 0, stream>>>(
                     cursor, dinvs, offs_g, csr_g, lps, b2, out, N);
}

// Round 12
// 194.855 us; speedup vs baseline: 1.1655x; 1.0820x over previous
//
#include <hip/hip_runtime.h>

#define N_FEATS 128
#define HIDDEN 512
#define NPAD 50176       // N rounded to multiple of 256
#define NBKT 196         // dst buckets of 256 nodes
#define SLAB 4608        // staging/csr slots per bucket (4096 avg + 8 sigma)
#define PA_EPB 4096      // bucketA edges per block
#define PA_BLOCKS 196    // ceil(800000/4096)
#define XH_BLOCKS 6250   // N*32 float4 units / 256

typedef __attribute__((ext_vector_type(4))) float floatx4;
typedef __attribute__((ext_vector_type(8))) short shortx8;
typedef __attribute__((ext_vector_type(8))) unsigned short ushortx8;

__device__ __forceinline__ unsigned short f2bf(float f) {
    union { float f; unsigned u; } a; a.f = f;
    unsigned r = a.u + 0x7fff + ((a.u >> 16) & 1);   // RNE
    return (unsigned short)(r >> 16);
}
#define BF(x) ({ union { unsigned u; float f; } _c; _c.u = (unsigned)(x) << 16; _c.f; })

// ---------------- K1: bucketA partition + W1 transpose + Xh convert ----------------
__global__ __launch_bounds__(256) void k_initA(const float* __restrict__ W1,
        unsigned short* __restrict__ w1t, const float* __restrict__ X,
        unsigned short* __restrict__ Xh, const int* __restrict__ src,
        const int* __restrict__ dst, int* __restrict__ bcur,
        unsigned* __restrict__ staging, int E, int N) {
    int b = blockIdx.x, tid = threadIdx.x;
    if (b < PA_BLOCKS) {
        __shared__ int hist[NBKT];
        __shared__ int base[NBKT];
        for (int i = tid; i < NBKT; i += 256) hist[i] = 0;
        __syncthreads();
        #pragma unroll
        for (int i = 0; i < 4; ++i) {
            int e = b * PA_EPB + (i * 256 + tid) * 4;
            if (e + 3 < E) {
                int4 d4 = *reinterpret_cast<const int4*>(dst + e);
                atomicAdd(&hist[d4.x >> 8], 1);
                atomicAdd(&hist[d4.y >> 8], 1);
                atomicAdd(&hist[d4.z >> 8], 1);
                atomicAdd(&hist[d4.w >> 8], 1);
            } else {
                for (int k = 0; k < 4; ++k)
                    if (e + k < E) atomicAdd(&hist[dst[e + k] >> 8], 1);
            }
        }
        __syncthreads();
        for (int i = tid; i < NBKT; i += 256) {
            int c = hist[i];
            base[i] = c ? atomicAdd(&bcur[i], c) : 0;
            hist[i] = 0;
        }
        __syncthreads();
        #pragma unroll
        for (int i = 0; i < 4; ++i) {
            int e = b * PA_EPB + (i * 256 + tid) * 4;
            if (e + 3 < E) {
                int4 d4 = *reinterpret_cast<const int4*>(dst + e);
                int4 s4 = *reinterpret_cast<const int4*>(src + e);
                #define PUT(dd, ss) { int bk = (dd) >> 8; int r = atomicAdd(&hist[bk], 1); \
                    int pos = base[bk] + r; if (pos < SLAB) \
                    staging[(size_t)bk * SLAB + pos] = ((unsigned)(ss) << 8) | (unsigned)((dd) & 255); }
                PUT(d4.x, s4.x) PUT(d4.y, s4.y) PUT(d4.z, s4.z) PUT(d4.w, s4.w)
            } else {
                for (int k = 0; k < 4; ++k)
                    if (e + k < E) { int dd = dst[e + k], ss = src[e + k]; PUT(dd, ss) }
                #undef PUT
            }
        }
    } else if (b < PA_BLOCKS + 16) {
        __shared__ unsigned short t[64][65];
        int bb = b - PA_BLOCKS;
        int ki = bb >> 3, ni = bb & 7;
        #pragma unroll
        for (int i = 0; i < 16; ++i) {
            int idx = tid + i * 256;
            int r = idx >> 6, c = idx & 63;
            t[r][c] = f2bf(W1[(ki * 64 + r) * 512 + ni * 64 + c]);
        }
        __syncthreads();
        #pragma unroll
        for (int i = 0; i < 16; ++i) {
            int idx = tid + i * 256;
            int rn = idx >> 6, ck = idx & 63;
            w1t[(ni * 64 + rn) * 128 + ki * 64 + ck] = t[ck][rn];
        }
    } else {
        int idx = (b - PA_BLOCKS - 16) * 256 + tid;
        if (idx < N * 32) {
            float4 v = reinterpret_cast<const float4*>(X)[idx];
            ushort4 o;
            o.x = f2bf(v.x); o.y = f2bf(v.y); o.z = f2bf(v.z); o.w = f2bf(v.w);
            reinterpret_cast<ushort4*>(Xh)[idx] = o;
        }
    }
}

// ---------------- K2: per-bucket compact-CSR build; emit offs_g/cursor/dinvs ----------------
__global__ __launch_bounds__(256) void k_bucketB(const int* __restrict__ bcur,
        const unsigned* __restrict__ staging, int* __restrict__ csr_g,
        int* __restrict__ offs_g, int* __restrict__ cursor, float* __restrict__ dinvs) {
    __shared__ int hist[256];
    __shared__ int offs_l[256];
    __shared__ int sc[256];
    int b = blockIdx.x, tid = threadIdx.x;
    hist[tid] = 0;
    __syncthreads();
    int cnt = bcur[b];
    if (cnt > SLAB) cnt = SLAB;
    const unsigned* st = staging + (size_t)b * SLAB;
    for (int j = tid; j < cnt; j += 256) atomicAdd(&hist[st[j] & 255u], 1);
    __syncthreads();
    int c = hist[tid];
    sc[tid] = c;
    __syncthreads();
    #pragma unroll
    for (int off = 1; off < 256; off <<= 1) {
        int t = (tid >= off) ? sc[tid - off] : 0;
        __syncthreads();
        sc[tid] += t;
        __syncthreads();
    }
    int excl = sc[tid] - c;
    offs_l[tid] = excl;
    int node = (b << 8) + tid;
    cursor[node] = c;
    dinvs[node] = rsqrtf((float)c + 1.0f);
    offs_g[node] = b * SLAB + excl;
    hist[tid] = 0;
    __syncthreads();
    for (int j = tid; j < cnt; j += 256) {
        unsigned v = st[j];
        int dl = (int)(v & 255u);
        int s = (int)(v >> 8);
        int p = atomicAdd(&hist[dl], 1);
        csr_g[b * SLAB + offs_l[dl] + p] = s;
    }
}

// ---------------- K3: fused gather + MFMA GEMM -> lps ----------------
// 392 blocks x 512 threads; 128 nodes/block. LDS = As(34.8K)+b1s+W2s = 41 KB.
// B from global (w1t L2-hot). No min-waves bound: let the allocator avoid spills;
// 3 blocks/CU if VGPR<=84, else 2 (round-9 floor).
__global__ __launch_bounds__(512) void k_gather_gemm(
        const int* __restrict__ cursor, const float* __restrict__ dinvs,
        const int* __restrict__ offs_g, const int* __restrict__ csr_g,
        const unsigned short* __restrict__ Xh, const unsigned short* __restrict__ w1t,
        const float* __restrict__ b1, const float* __restrict__ W2,
        float2* __restrict__ lps, int N) {
    __shared__ unsigned short As[128][136];   // 34.8 KB
    __shared__ float b1s[HIDDEN];             // 2 KB
    __shared__ float W2s[HIDDEN * 2];         // 4 KB

    const int tid = threadIdx.x;
    const int m0 = blockIdx.x * 128;
    for (int i = tid; i < HIDDEN; i += 512) b1s[i] = b1[i];
    for (int i = tid; i < HIDDEN * 2; i += 512) W2s[i] = W2[i];

    union U8 { ushortx8 v; unsigned short s[8]; };

    // ---- gather phase: 4 passes x (32 nodes x 16 lanes); 1 b128/lane covers a 256B row ----
    const int lane16 = tid & 15;
    const int nsub = tid >> 4;                 // 0..31
    const ushortx8* Xv = reinterpret_cast<const ushortx8*>(Xh);
    #pragma unroll
    for (int h = 0; h < 4; ++h) {
        int r = h * 32 + nsub;
        int gm = m0 + r;
        if (gm < N) {
            float dv = dinvs[gm];
            int beg = offs_g[gm];
            int cnt = cursor[gm];
            U8 sv; sv.v = Xv[((size_t)gm << 4) + lane16];
            float a[8];
            #pragma unroll
            for (int k = 0; k < 8; ++k) a[k] = dv * BF(sv.s[k]);
            const int* cp = csr_g + beg;
            int j = 0;
            int4 nxt;
            if (cnt >= 4) nxt = *reinterpret_cast<const int4*>(cp);
            for (; j + 4 <= cnt; j += 4) {
                int4 s4 = nxt;
                if (j + 8 <= cnt) nxt = *reinterpret_cast<const int4*>(cp + j + 4);
                float w0 = dinvs[s4.x], w1 = dinvs[s4.y], w2 = dinvs[s4.z], w3 = dinvs[s4.w];
                U8 u0, u1, u2, u3;
                u0.v = Xv[((size_t)s4.x << 4) + lane16];
                u1.v = Xv[((size_t)s4.y << 4) + lane16];
                u2.v = Xv[((size_t)s4.z << 4) + lane16];
                u3.v = Xv[((size_t)s4.w << 4) + lane16];
                #pragma unroll
                for (int k = 0; k < 8; ++k)
                    a[k] += w0 * BF(u0.s[k]) + w1 * BF(u1.s[k]) + w2 * BF(u2.s[k]) + w3 * BF(u3.s[k]);
            }
            for (; j < cnt; ++j) {
                int s = cp[j];
                float w = dinvs[s];
                U8 u; u.v = Xv[((size_t)s << 4) + lane16];
                #pragma unroll
                for (int k = 0; k < 8; ++k) a[k] += w * BF(u.s[k]);
            }
            union { shortx8 v; unsigned short s[8]; } o;
            #pragma unroll
            for (int k = 0; k < 8; ++k) o.s[k] = f2bf(a[k] * dv);
            *reinterpret_cast<shortx8*>(&As[r][lane16 * 8]) = o.v;
        } else {
            shortx8 z = {0, 0, 0, 0, 0, 0, 0, 0};
            *reinterpret_cast<shortx8*>(&As[r][lane16 * 8]) = z;
        }
    }
    __syncthreads();

    // ---- GEMM phase: 8 waves x 16-row strips; B from global; n0 loop rolled ----
    const int wave = tid >> 6;
    const int lane64 = tid & 63;
    const int quad = lane64 >> 4;
    const int l16 = lane64 & 15;
    const unsigned short* wb = w1t + (size_t)l16 * 128 + quad * 8;

    float accL0[4] = {0.f, 0.f, 0.f, 0.f};
    float accL1[4] = {0.f, 0.f, 0.f, 0.f};

    for (int n0 = 0; n0 < HIDDEN; n0 += 128) {
        floatx4 acc[8];
        #pragma unroll
        for (int nt = 0; nt < 8; ++nt) acc[nt] = (floatx4){0.f, 0.f, 0.f, 0.f};

        #pragma unroll
        for (int ks = 0; ks < 4; ++ks) {
            shortx8 af = *reinterpret_cast<const shortx8*>(&As[wave * 16 + l16][ks * 32 + quad * 8]);
            #pragma unroll
            for (int nt = 0; nt < 8; ++nt) {
                shortx8 bf = *reinterpret_cast<const shortx8*>(wb + (size_t)(n0 + nt * 16) * 128 + ks * 32);
                acc[nt] = __builtin_amdgcn_mfma_f32_16x16x32_bf16(af, bf, acc[nt], 0, 0, 0);
            }
        }

        #pragma unroll
        for (int nt = 0; nt < 8; ++nt) {
            int col = n0 + nt * 16 + l16;
            float bb = b1s[col];
            float w20 = W2s[col * 2 + 0];
            float w21 = W2s[col * 2 + 1];
            #pragma unroll
            for (int r = 0; r < 4; ++r) {
                float hh = acc[nt][r] + bb;
                hh = hh > 0.f ? hh : 0.f;
                accL0[r] += hh * w20;
                accL1[r] += hh * w21;
            }
        }
    }

    #pragma unroll
    for (int off = 1; off < 16; off <<= 1) {
        #pragma unroll
        for (int r = 0; r < 4; ++r) {
            accL0[r] += __shfl_xor(accL0[r], off);
            accL1[r] += __shfl_xor(accL1[r], off);
        }
    }
    if (l16 == 0) {
        #pragma unroll
        for (int r = 0; r < 4; ++r) {
            int gm = m0 + wave * 16 + quad * 4 + r;
            if (gm < N) {
                float dv = dinvs[gm];
                lps[gm] = make_float2(dv * accL0[r], dv * accL1[r]);
            }
        }
    }
}

// ---------------- K4: layer-2 CSR gather + self-loop + bias + softmax (4 lanes/node) ----------------
__global__ __launch_bounds__(256) void k_final(const int* __restrict__ cursor,
        const float* __restrict__ dinvs, const int* __restrict__ offs_g,
        const int* __restrict__ csr_g, const float2* __restrict__ lps,
        const float* __restrict__ b2, float* __restrict__ out, int N) {
    int t = blockIdx.x * 256 + threadIdx.x;
    int node = t >> 2;
    int lane = t & 3;
    if (node >= N) return;
    int cnt = cursor[node];
    int beg = offs_g[node];
    float a0 = 0.f, a1 = 0.f;
    for (int j = lane; j < cnt; j += 4) {
        float2 v = lps[csr_g[beg + j]];
        a0 += v.x;
        a1 += v.y;
    }
    #pragma unroll
    for (int off = 1; off < 4; off <<= 1) {
        a0 += __shfl_xor(a0, off);
        a1 += __shfl_xor(a1, off);
    }
    if (lane == 0) {
        float dv = dinvs[node];
        float2 self = lps[node];
        float l0 = dv * (a0 + self.x) + b2[0];
        float l1 = dv * (a1 + self.y) + b2[1];
        float m = fmaxf(l0, l1);
        float e0 = __expf(l0 - m), e1 = __expf(l1 - m);
        float inv = 1.0f / (e0 + e1);
        out[(size_t)node * 2 + 0] = e0 * inv;
        out[(size_t)node * 2 + 1] = e1 * inv;
    }
}

extern "C" void kernel_launch(void* const* d_in, const int* in_sizes, int n_in,
                              void* d_out, int out_size, void* d_ws, size_t ws_size,
                              hipStream_t stream) {
    const float* X  = (const float*)d_in[0];
    const int* ei   = (const int*)d_in[1];
    const float* W1 = (const float*)d_in[2];
    const float* b1 = (const float*)d_in[3];
    const float* W2 = (const float*)d_in[4];
    const float* b2 = (const float*)d_in[5];
    float* out = (float*)d_out;

    const int N = in_sizes[0] / N_FEATS;   // 50000
    const int E = in_sizes[1] / 2;         // 800000
    const int* src = ei;
    const int* dst = ei + E;

    // workspace layout (16B-aligned segments), ~22 MB
    int* cursor  = (int*)d_ws;                                   // NPAD
    int* bcur    = cursor + NPAD;                                // 256
    int* offs_g  = bcur + 256;                                   // NPAD
    float* dinvs = (float*)(offs_g + NPAD);                      // NPAD
    float2* lps  = (float2*)(dinvs + NPAD);                      // NPAD float2
    unsigned short* w1t = (unsigned short*)(lps + NPAD);         // 512*128
    unsigned short* Xh  = w1t + 512 * 128;                       // NPAD*128
    unsigned* staging = (unsigned*)(Xh + (size_t)NPAD * 128);    // NBKT*SLAB
    int* csr_g   = (int*)(staging + (size_t)NBKT * SLAB);        // NBKT*SLAB

    hipMemsetAsync(bcur, 0, 256 * sizeof(int), stream);
    k_initA      <<<PA_BLOCKS + 16 + XH_BLOCKS, 256, 0, stream>>>(
                     W1, w1t, X, Xh, src, dst, bcur, staging, E, N);
    k_bucketB    <<<NBKT, 256, 0, stream>>>(bcur, staging, csr_g, offs_g, cursor, dinvs);
    k_gather_gemm<<<NPAD / 128, 512, 0, stream>>>(cursor, dinvs, offs_g, csr_g,
                     Xh, w1t, b1, W2, lps, N);
    k_final      <<<((size_t)N * 4 + 255) / 256, 256, 0, stream>>>(
                     cursor, dinvs, offs_g, csr_g, lps, b2, out, N);
}

// Round 13
// 149.373 us; speedup vs baseline: 1.5204x; 1.3045x over previous
//
#include <hip/hip_runtime.h>

#define N_FEATS 128
#define HIDDEN 512
#define NPAD 50176       // N rounded to multiple of 256
#define NBKT 196         // dst buckets of 256 nodes
#define SLAB 4608        // staging/csr slots per bucket (4096 avg + 8 sigma)
#define PA_EPB 4096      // bucketA edges per block
#define PA_BLOCKS 196    // ceil(800000/4096)
#define XQ_BLOCKS 3125   // ceil(50000/16) quantize blocks (16 rows each)

typedef __attribute__((ext_vector_type(4))) float floatx4;
typedef __attribute__((ext_vector_type(8))) short shortx8;

__device__ __forceinline__ unsigned short f2bf(float f) {
    union { float f; unsigned u; } a; a.f = f;
    unsigned r = a.u + 0x7fff + ((a.u >> 16) & 1);   // RNE
    return (unsigned short)(r >> 16);
}

// ---------------- K1: bucketA partition + W1 transpose + X int8 quantize ----------------
__global__ __launch_bounds__(256) void k_initA(const float* __restrict__ W1,
        unsigned short* __restrict__ w1t, const float* __restrict__ X,
        signed char* __restrict__ Xq, float* __restrict__ scale,
        const int* __restrict__ src, const int* __restrict__ dst,
        int* __restrict__ bcur, unsigned* __restrict__ staging, int E, int N) {
    int b = blockIdx.x, tid = threadIdx.x;
    if (b < PA_BLOCKS) {
        __shared__ int hist[NBKT];
        __shared__ int base[NBKT];
        for (int i = tid; i < NBKT; i += 256) hist[i] = 0;
        __syncthreads();
        #pragma unroll
        for (int i = 0; i < 4; ++i) {
            int e = b * PA_EPB + (i * 256 + tid) * 4;
            if (e + 3 < E) {
                int4 d4 = *reinterpret_cast<const int4*>(dst + e);
                atomicAdd(&hist[d4.x >> 8], 1);
                atomicAdd(&hist[d4.y >> 8], 1);
                atomicAdd(&hist[d4.z >> 8], 1);
                atomicAdd(&hist[d4.w >> 8], 1);
            } else {
                for (int k = 0; k < 4; ++k)
                    if (e + k < E) atomicAdd(&hist[dst[e + k] >> 8], 1);
            }
        }
        __syncthreads();
        for (int i = tid; i < NBKT; i += 256) {
            int c = hist[i];
            base[i] = c ? atomicAdd(&bcur[i], c) : 0;
            hist[i] = 0;
        }
        __syncthreads();
        #pragma unroll
        for (int i = 0; i < 4; ++i) {
            int e = b * PA_EPB + (i * 256 + tid) * 4;
            if (e + 3 < E) {
                int4 d4 = *reinterpret_cast<const int4*>(dst + e);
                int4 s4 = *reinterpret_cast<const int4*>(src + e);
                #define PUT(dd, ss) { int bk = (dd) >> 8; int r = atomicAdd(&hist[bk], 1); \
                    int pos = base[bk] + r; if (pos < SLAB) \
                    staging[(size_t)bk * SLAB + pos] = ((unsigned)(ss) << 8) | (unsigned)((dd) & 255); }
                PUT(d4.x, s4.x) PUT(d4.y, s4.y) PUT(d4.z, s4.z) PUT(d4.w, s4.w)
            } else {
                for (int k = 0; k < 4; ++k)
                    if (e + k < E) { int dd = dst[e + k], ss = src[e + k]; PUT(dd, ss) }
                #undef PUT
            }
        }
    } else if (b < PA_BLOCKS + 16) {
        __shared__ unsigned short t[64][65];
        int bb = b - PA_BLOCKS;
        int ki = bb >> 3, ni = bb & 7;
        #pragma unroll
        for (int i = 0; i < 16; ++i) {
            int idx = tid + i * 256;
            int r = idx >> 6, c = idx & 63;
            t[r][c] = f2bf(W1[(ki * 64 + r) * 512 + ni * 64 + c]);
        }
        __syncthreads();
        #pragma unroll
        for (int i = 0; i < 16; ++i) {
            int idx = tid + i * 256;
            int rn = idx >> 6, ck = idx & 63;
            w1t[(ni * 64 + rn) * 128 + ki * 64 + ck] = t[ck][rn];
        }
    } else {
        // int8 quantize: 16 rows/block, 16 lanes/row, 8 feats/lane
        int r = (b - PA_BLOCKS - 16) * 16 + (tid >> 4);
        int lane = tid & 15;
        if (r < N) {
            const float* xp = X + (size_t)r * N_FEATS + lane * 8;
            float4 v0 = *reinterpret_cast<const float4*>(xp);
            float4 v1 = *reinterpret_cast<const float4*>(xp + 4);
            float f[8] = {v0.x, v0.y, v0.z, v0.w, v1.x, v1.y, v1.z, v1.w};
            float mx = 0.f;
            #pragma unroll
            for (int k = 0; k < 8; ++k) mx = fmaxf(mx, fabsf(f[k]));
            #pragma unroll
            for (int off = 1; off < 16; off <<= 1) mx = fmaxf(mx, __shfl_xor(mx, off));
            float rs = (mx > 0.f) ? 127.0f / mx : 0.f;
            union { signed char c[8]; uint2 u; } o;
            #pragma unroll
            for (int k = 0; k < 8; ++k) {
                int q = (int)rintf(f[k] * rs);
                q = q > 127 ? 127 : (q < -127 ? -127 : q);
                o.c[k] = (signed char)q;
            }
            *reinterpret_cast<uint2*>(Xq + (size_t)r * N_FEATS + lane * 8) = o.u;
            if (lane == 0) scale[r] = (mx > 0.f) ? mx / 127.0f : 0.f;
        }
    }
}

// ---------------- K2: per-bucket compact-CSR build; emit offs_g/cursor/dinvs/dscale ----------------
__global__ __launch_bounds__(256) void k_bucketB(const int* __restrict__ bcur,
        const unsigned* __restrict__ staging, const float* __restrict__ scale,
        int* __restrict__ csr_g, int* __restrict__ offs_g,
        int* __restrict__ cursor, float* __restrict__ dinvs, float* __restrict__ dscale) {
    __shared__ int hist[256];
    __shared__ int offs_l[256];
    __shared__ int sc[256];
    int b = blockIdx.x, tid = threadIdx.x;
    hist[tid] = 0;
    __syncthreads();
    int cnt = bcur[b];
    if (cnt > SLAB) cnt = SLAB;
    const unsigned* st = staging + (size_t)b * SLAB;
    for (int j = tid; j < cnt; j += 256) atomicAdd(&hist[st[j] & 255u], 1);
    __syncthreads();
    int c = hist[tid];
    sc[tid] = c;
    __syncthreads();
    #pragma unroll
    for (int off = 1; off < 256; off <<= 1) {
        int t = (tid >= off) ? sc[tid - off] : 0;
        __syncthreads();
        sc[tid] += t;
        __syncthreads();
    }
    int excl = sc[tid] - c;
    offs_l[tid] = excl;
    int node = (b << 8) + tid;
    float dv = rsqrtf((float)c + 1.0f);
    cursor[node] = c;
    dinvs[node] = dv;
    dscale[node] = dv * scale[node];
    offs_g[node] = b * SLAB + excl;
    hist[tid] = 0;
    __syncthreads();
    for (int j = tid; j < cnt; j += 256) {
        unsigned v = st[j];
        int dl = (int)(v & 255u);
        int s = (int)(v >> 8);
        int p = atomicAdd(&hist[dl], 1);
        csr_g[b * SLAB + offs_l[dl] + p] = s;
    }
}

// ---------------- K3: fused int8-gather + MFMA GEMM (Bs in LDS) -> lps ----------------
// 392 blocks x 512 threads; 128 nodes/block; LDS 75 KB -> 2 blocks/CU (round-9 structure).
__global__ __launch_bounds__(512, 4) void k_gather_gemm(
        const int* __restrict__ cursor, const float* __restrict__ dinvs,
        const float* __restrict__ dscale, const int* __restrict__ offs_g,
        const int* __restrict__ csr_g, const signed char* __restrict__ Xq,
        const unsigned short* __restrict__ w1t, const float* __restrict__ b1,
        const float* __restrict__ W2, float2* __restrict__ lps, int N) {
    __shared__ unsigned short As[128][136];   // 34.8 KB
    __shared__ unsigned short Bs[128][136];   // 34.8 KB
    __shared__ float b1s[HIDDEN];
    __shared__ float W2s[HIDDEN * 2];

    const int tid = threadIdx.x;
    const int m0 = blockIdx.x * 128;
    for (int i = tid; i < HIDDEN; i += 512) b1s[i] = b1[i];
    for (int i = tid; i < HIDDEN * 2; i += 512) W2s[i] = W2[i];

    union Q8 { uint2 u; signed char c[8]; };

    // ---- gather: 4 passes x (32 nodes x 16 lanes); 8 int8 per lane = full 128B row ----
    const int lane16 = tid & 15;
    const int nsub = tid >> 4;                 // 0..31
    #pragma unroll
    for (int h = 0; h < 4; ++h) {
        int r = h * 32 + nsub;
        int gm = m0 + r;
        if (gm < N) {
            float dv = dinvs[gm];
            float ds = dscale[gm];
            int beg = offs_g[gm];
            int cnt = cursor[gm];
            const signed char* xrow = Xq + (size_t)gm * N_FEATS + lane16 * 8;
            Q8 sv; sv.u = *reinterpret_cast<const uint2*>(xrow);
            float a[8];
            #pragma unroll
            for (int k = 0; k < 8; ++k) a[k] = ds * (float)sv.c[k];
            const int* cp = csr_g + beg;
            int j = 0;
            int4 nxt;
            if (cnt >= 4) nxt = *reinterpret_cast<const int4*>(cp);
            for (; j + 4 <= cnt; j += 4) {
                int4 s4 = nxt;
                if (j + 8 <= cnt) nxt = *reinterpret_cast<const int4*>(cp + j + 4);
                float w0 = dscale[s4.x], w1 = dscale[s4.y], w2 = dscale[s4.z], w3 = dscale[s4.w];
                Q8 u0, u1, u2, u3;
                u0.u = *reinterpret_cast<const uint2*>(Xq + (size_t)s4.x * N_FEATS + lane16 * 8);
                u1.u = *reinterpret_cast<const uint2*>(Xq + (size_t)s4.y * N_FEATS + lane16 * 8);
                u2.u = *reinterpret_cast<const uint2*>(Xq + (size_t)s4.z * N_FEATS + lane16 * 8);
                u3.u = *reinterpret_cast<const uint2*>(Xq + (size_t)s4.w * N_FEATS + lane16 * 8);
                #pragma unroll
                for (int k = 0; k < 8; ++k)
                    a[k] += w0 * (float)u0.c[k] + w1 * (float)u1.c[k]
                          + w2 * (float)u2.c[k] + w3 * (float)u3.c[k];
            }
            for (; j < cnt; ++j) {
                int s = cp[j];
                float w = dscale[s];
                Q8 u; u.u = *reinterpret_cast<const uint2*>(Xq + (size_t)s * N_FEATS + lane16 * 8);
                #pragma unroll
                for (int k = 0; k < 8; ++k) a[k] += w * (float)u.c[k];
            }
            union { shortx8 v; unsigned short s[8]; } o;
            #pragma unroll
            for (int k = 0; k < 8; ++k) o.s[k] = f2bf(a[k] * dv);
            *reinterpret_cast<shortx8*>(&As[r][lane16 * 8]) = o.v;
        } else {
            shortx8 z = {0, 0, 0, 0, 0, 0, 0, 0};
            *reinterpret_cast<shortx8*>(&As[r][lane16 * 8]) = z;
        }
    }
    __syncthreads();

    // ---- GEMM phase (round-9 structure): 8 waves x 16-row strips; Bs staged in LDS ----
    const int wave = tid >> 6;
    const int lane64 = tid & 63;
    const int quad = lane64 >> 4;
    const int l16 = lane64 & 15;

    float accL0[4] = {0.f, 0.f, 0.f, 0.f};
    float accL1[4] = {0.f, 0.f, 0.f, 0.f};

    for (int n0 = 0; n0 < HIDDEN; n0 += 128) {
        #pragma unroll
        for (int it = 0; it < 4; ++it) {
            int flat = (tid + it * 512) * 8;
            int r = flat >> 7, c = flat & 127;
            *reinterpret_cast<shortx8*>(&Bs[r][c]) =
                *reinterpret_cast<const shortx8*>(w1t + (size_t)(n0 + r) * 128 + c);
        }
        __syncthreads();

        floatx4 acc[8];
        #pragma unroll
        for (int nt = 0; nt < 8; ++nt) acc[nt] = (floatx4){0.f, 0.f, 0.f, 0.f};

        #pragma unroll
        for (int ks = 0; ks < 4; ++ks) {
            shortx8 af = *reinterpret_cast<const shortx8*>(&As[wave * 16 + l16][ks * 32 + quad * 8]);
            #pragma unroll
            for (int nt = 0; nt < 8; ++nt) {
                shortx8 bf = *reinterpret_cast<const shortx8*>(&Bs[nt * 16 + l16][ks * 32 + quad * 8]);
                acc[nt] = __builtin_amdgcn_mfma_f32_16x16x32_bf16(af, bf, acc[nt], 0, 0, 0);
            }
        }

        #pragma unroll
        for (int nt = 0; nt < 8; ++nt) {
            int col = n0 + nt * 16 + l16;
            float bb = b1s[col];
            float w20 = W2s[col * 2 + 0];
            float w21 = W2s[col * 2 + 1];
            #pragma unroll
            for (int r = 0; r < 4; ++r) {
                float hh = acc[nt][r] + bb;
                hh = hh > 0.f ? hh : 0.f;
                accL0[r] += hh * w20;
                accL1[r] += hh * w21;
            }
        }
        __syncthreads();
    }

    #pragma unroll
    for (int off = 1; off < 16; off <<= 1) {
        #pragma unroll
        for (int r = 0; r < 4; ++r) {
            accL0[r] += __shfl_xor(accL0[r], off);
            accL1[r] += __shfl_xor(accL1[r], off);
        }
    }
    if (l16 == 0) {
        #pragma unroll
        for (int r = 0; r < 4; ++r) {
            int gm = m0 + wave * 16 + quad * 4 + r;
            if (gm < N) {
                float dv = dinvs[gm];
                lps[gm] = make_float2(dv * accL0[r], dv * accL1[r]);
            }
        }
    }
}

// ---------------- K4: layer-2 CSR gather + self-loop + bias + softmax (4 lanes/node) ----------------
__global__ __launch_bounds__(256) void k_final(const int* __restrict__ cursor,
        const float* __restrict__ dinvs, const int* __restrict__ offs_g,
        const int* __restrict__ csr_g, const float2* __restrict__ lps,
        const float* __restrict__ b2, float* __restrict__ out, int N) {
    int t = blockIdx.x * 256 + threadIdx.x;
    int node = t >> 2;
    int lane = t & 3;
    if (node >= N) return;
    int cnt = cursor[node];
    int beg = offs_g[node];
    float a0 = 0.f, a1 = 0.f;
    for (int j = lane; j < cnt; j += 4) {
        float2 v = lps[csr_g[beg + j]];
        a0 += v.x;
        a1 += v.y;
    }
    #pragma unroll
    for (int off = 1; off < 4; off <<= 1) {
        a0 += __shfl_xor(a0, off);
        a1 += __shfl_xor(a1, off);
    }
    if (lane == 0) {
        float dv = dinvs[node];
        float2 self = lps[node];
        float l0 = dv * (a0 + self.x) + b2[0];
        float l1 = dv * (a1 + self.y) + b2[1];
        float m = fmaxf(l0, l1);
        float e0 = __expf(l0 - m), e1 = __expf(l1 - m);
        float inv = 1.0f / (e0 + e1);
        out[(size_t)node * 2 + 0] = e0 * inv;
        out[(size_t)node * 2 + 1] = e1 * inv;
    }
}

extern "C" void kernel_launch(void* const* d_in, const int* in_sizes, int n_in,
                              void* d_out, int out_size, void* d_ws, size_t ws_size,
                              hipStream_t stream) {
    const float* X  = (const float*)d_in[0];
    const int* ei   = (const int*)d_in[1];
    const float* W1 = (const float*)d_in[2];
    const float* b1 = (const float*)d_in[3];
    const float* W2 = (const float*)d_in[4];
    const float* b2 = (const float*)d_in[5];
    float* out = (float*)d_out;

    const int N = in_sizes[0] / N_FEATS;   // 50000
    const int E = in_sizes[1] / 2;         // 800000
    const int* src = ei;
    const int* dst = ei + E;

    // workspace layout (16B-aligned segments), ~16 MB
    int* cursor  = (int*)d_ws;                                   // NPAD
    int* bcur    = cursor + NPAD;                                // 256
    int* offs_g  = bcur + 256;                                   // NPAD
    float* dinvs = (float*)(offs_g + NPAD);                      // NPAD
    float* dscale = dinvs + NPAD;                                // NPAD
    float* scale = dscale + NPAD;                                // NPAD
    float2* lps  = (float2*)(scale + NPAD);                      // NPAD float2
    unsigned short* w1t = (unsigned short*)(lps + NPAD);         // 512*128
    signed char* Xq = (signed char*)(w1t + 512 * 128);           // NPAD*128 int8
    unsigned* staging = (unsigned*)(Xq + (size_t)NPAD * 128);    // NBKT*SLAB
    int* csr_g   = (int*)(staging + (size_t)NBKT * SLAB);        // NBKT*SLAB

    hipMemsetAsync(bcur, 0, 256 * sizeof(int), stream);
    k_initA      <<<PA_BLOCKS + 16 + XQ_BLOCKS, 256, 0, stream>>>(
                     W1, w1t, X, Xq, scale, src, dst, bcur, staging, E, N);
    k_bucketB    <<<NBKT, 256, 0, stream>>>(bcur, staging, scale, csr_g, offs_g,
                     cursor, dinvs, dscale);
    k_gather_gemm<<<NPAD / 128, 512, 0, stream>>>(cursor, dinvs, dscale, offs_g, csr_g,
                     Xq, w1t, b1, W2, lps, N);
    k_final      <<<((size_t)N * 4 + 255) / 256, 256, 0, stream>>>(
                     cursor, dinvs, offs_g, csr_g, lps, b2, out, N);
}